// Round 16
// baseline (25.216 us; speedup 1.0000x reference)
//
#include <hip/hip_runtime.h>
#include <hip/hip_bf16.h>

#define EPS 1e-07f

#define BLOCK   512         // splat block (8 waves)
#define RPB     64          // rays per block (2 per thread: IPT=2)
#define SLICE_G 512         // Gaussians per K-slice
#define NGRP    (SLICE_G/4) // 128 groups per slice
#define NCHUNK  16          // chunks per slice (wv<<1 | half)
#define NG      (NGRP/NCHUNK) // 8 groups per chunk
#define NW      (BLOCK/64)  // 8 waves
#define PBLOCK  64          // precompute block size

// sqrt(0.5*log2(e)) ; log2(sqrt(2*pi))
#define SQRT_HALF_LOG2E 0.84932180028801904f
#define LOG2_SQRT_2PI   1.32574806473616588f

typedef float v4f __attribute__((ext_vector_type(4)));

// ---------------------------------------------------------------------------
// Kernel 1: one-shot per-Gaussian precompute + zero d_out.
// Cross-product identity: c0 - b^2/a = (u x (p-pos))^2 / a',  a' = u^T(S/detS)u
// Group-interleaved table gG[group][24]:
//   [0..3]=m00' [4..7]=m01' [8..11]=m11' [12..15]=cc [16..19]=pos0 [20..23]=pos1
// Pad records (k >= K): cc = -1e38 -> exp2 -> exactly 0 contribution.
// ---------------------------------------------------------------------------
__global__ __launch_bounds__(PBLOCK) void precompute_gauss(
                                 const float* __restrict__ pos_raw,
                                 const float* __restrict__ conc_raw,
                                 const float* __restrict__ scale_raw,
                                 const float* __restrict__ rot_raw,
                                 const void*  __restrict__ map_size_p,
                                 float* __restrict__ gG,
                                 float* __restrict__ out,
                                 int K, int KPAD, int R)
{
    int k = blockIdx.x * blockDim.x + threadIdx.x;
    int nthreads = gridDim.x * blockDim.x;

    // Zero the output (ordered before splat_main on the same stream).
    for (int i = k; i < R; i += nthreads) out[i] = 0.0f;

    if (k >= KPAD) return;

    const int q = k >> 2, e = k & 3;
    float* rec = gG + q * 24;

    if (k >= K) {               // pad: contributes exactly 0
        rec[0  + e] = 1.0f;
        rec[4  + e] = 0.0f;
        rec[8  + e] = 1.0f;
        rec[12 + e] = -1e38f;
        rec[16 + e] = 0.0f;
        rec[20 + e] = 0.0f;
        return;
    }

    // map_size may arrive as int32 or float32 single-element array.
    unsigned int msbits = *(const unsigned int*)map_size_p;
    float msf = __uint_as_float(msbits);
    const float ms = (msf >= 1e-3f && msf <= 1e9f) ? msf
                                                   : (float)(*(const int*)map_size_p);

    float pr0 = pos_raw[2*k],  pr1 = pos_raw[2*k+1];
    float pos0 = ms / (1.0f + __expf(-pr0));   // sigmoid * map_size
    float pos1 = ms / (1.0f + __expf(-pr1));

    float cr = conc_raw[k];
    float conc = fmaxf(cr, 0.0f) + __logf(1.0f + __expf(-fabsf(cr)));  // softplus

    float s0 = __expf(scale_raw[2*k]);
    float s1 = __expf(scale_raw[2*k+1]);
    float d0 = 1.0f / (s0*s0 + EPS);
    float d1 = 1.0f / (s1*s1 + EPS);

    float rot = rot_raw[k];
    float c = __cosf(rot), s = __sinf(rot);

    float m00 = c*c*d0 + s*s*d1;
    float m01 = c*s*(d0 - d1);
    float m11 = s*s*d0 + c*c*d1;

    float det    = d0 * d1;
    float invdet = 1.0f / det;
    float cc = __log2f(conc) + LOG2_SQRT_2PI - 0.5f * __log2f(det);

    rec[0  + e] = m00 * invdet;
    rec[4  + e] = m01 * invdet;
    rec[8  + e] = m11 * invdet;
    rec[12 + e] = cc;
    rec[16 + e] = pos0;
    rec[20 + e] = pos1;
}

// ---------------------------------------------------------------------------
// Kernel 2: splat, IPT=2. grid = (R/64 ray-groups) x (KPAD/512 K-slices)
// = 128 x 8 = 1024 blocks x 512 thr = 4 blocks/CU (32 waves/CU, 8/SIMD).
// Each thread owns TWO rays (base+(lane&31), base+32+(lane&31)), so each
// 6 x ds_read_b128 group feeds 8 pair-computations (was 4) — per-pair
// LDS+loop cost halves while occupancy stays at full 8 waves/SIMD.
// Inner math identical to R8/R15 (verified): t = cr*rsq(a'); dens = rsq *
// 2^(cc - t^2). Reduction: shfl_xor(32) merges same-ray chunk halves,
// LDS tree over 8 waves, one atomicAdd per (ray, slice).
// ---------------------------------------------------------------------------
__global__ __launch_bounds__(BLOCK, 8) void splat_main(
        const float* __restrict__ p_rays,
        const float* __restrict__ u_rays,
        const float* __restrict__ gG,
        float* __restrict__ out,
        int R)
{
    __shared__ v4f  sG4[NGRP * 6];      // 12 KB
    __shared__ float psum[NW][RPB];     // 2 KB

    const int tid   = threadIdx.x;
    const int lane  = tid & 63;
    const int wv    = tid >> 6;         // 0..7
    const int rayl  = lane & 31;
    const int half  = lane >> 5;        // 0/1
    const int chunk = (wv << 1) | half; // 0..15

    const int rbase = blockIdx.x * RPB;
    int ray0 = rbase + rayl;
    int ray1 = rbase + 32 + rayl;
    if (ray0 >= R) ray0 = R - 1;        // defensive; R % RPB == 0 normally
    if (ray1 >= R) ray1 = R - 1;

    // ---- stage this slice's table (NGRP*6 v4f = 12 KB) ----
    {
        const v4f* src = (const v4f*)(gG + (size_t)blockIdx.y * NGRP * 24);
        for (int i = tid; i < NGRP * 6; i += BLOCK)
            sG4[i] = src[i];
    }

    // Per-ray coefficients for both rays (overlaps staging latency).
    float qu0[2], qu1[2], qu2[2], wt[2], su1[2], nsu0[2];
    #pragma unroll
    for (int r = 0; r < 2; ++r) {
        int ray = r ? ray1 : ray0;
        float2 p2 = *(const float2*)(p_rays + 2*ray);
        float2 u2 = *(const float2*)(u_rays + 2*ray);
        float p0 = p2.x, p1 = p2.y, u0 = u2.x, u1 = u2.y;
        qu0[r]  = u0*u0;
        qu1[r]  = 2.0f*u0*u1;
        qu2[r]  = u1*u1;
        wt[r]   =  SQRT_HALF_LOG2E * (u0*p1 - u1*p0);
        su1[r]  =  SQRT_HALF_LOG2E * u1;
        nsu0[r] = -SQRT_HALF_LOG2E * u0;
    }

    __syncthreads();

    // ---- walk this wave-half's chunk (NG=8 groups) ----
    float acc0 = 0.0f, acc1 = 0.0f;
    const int g0 = chunk * NG;
    #pragma unroll 2
    for (int gq = 0; gq < NG; ++gq) {
        const v4f* g = &sG4[(g0 + gq) * 6];
        v4f M00 = g[0];
        v4f M01 = g[1];
        v4f M11 = g[2];
        v4f CC  = g[3];
        v4f P0  = g[4];
        v4f P1  = g[5];

        #pragma unroll
        for (int e = 0; e < 4; ++e) {
            // ray 0
            {
                float a_  = fmaf(qu2[0], M11[e], fmaf(qu1[0], M01[e], qu0[0] * M00[e]));
                float cr_ = fmaf(nsu0[0], P1[e], fmaf(su1[0], P0[e], wt[0]));
                float ra_ = __builtin_amdgcn_rsqf(a_);
                float t_  = cr_ * ra_;
                float ar_ = fmaf(-t_, t_, CC[e]);
                float e_  = __builtin_amdgcn_exp2f(ar_);
                acc0 = fmaf(ra_, e_, acc0);
            }
            // ray 1 (reuses the staged group)
            {
                float a_  = fmaf(qu2[1], M11[e], fmaf(qu1[1], M01[e], qu0[1] * M00[e]));
                float cr_ = fmaf(nsu0[1], P1[e], fmaf(su1[1], P0[e], wt[1]));
                float ra_ = __builtin_amdgcn_rsqf(a_);
                float t_  = cr_ * ra_;
                float ar_ = fmaf(-t_, t_, CC[e]);
                float e_  = __builtin_amdgcn_exp2f(ar_);
                acc1 = fmaf(ra_, e_, acc1);
            }
        }
    }

    // ---- reduction ----
    // shfl_xor(32): partner lane has same rayl, other chunk-half -> merge.
    acc0 += __shfl_xor(acc0, 32, 64);
    acc1 += __shfl_xor(acc1, 32, 64);
    if (half == 0) {
        psum[wv][rayl]      = acc0;
        psum[wv][rayl + 32] = acc1;
    }
    __syncthreads();

    if (wv == 0) {                       // lanes 0..63 cover all 64 rays
        float s = 0.0f;
        #pragma unroll
        for (int w = 0; w < NW; ++w) s += psum[w][lane];
        int oray = rbase + lane;
        if (oray < R) atomicAdd(&out[oray], s);
    }
}

// ---------------------------------------------------------------------------
extern "C" void kernel_launch(void* const* d_in, const int* in_sizes, int n_in,
                              void* d_out, int out_size, void* d_ws, size_t ws_size,
                              hipStream_t stream)
{
    const float* pos_raw   = (const float*)d_in[0];
    const float* conc_raw  = (const float*)d_in[1];
    const float* scale_raw = (const float*)d_in[2];
    const float* rot_raw   = (const float*)d_in[3];
    const float* p_rays    = (const float*)d_in[4];
    const float* u_rays    = (const float*)d_in[5];
    const void*  map_size  = d_in[6];

    const int K = in_sizes[1];          // conc_raw is (K,)
    const int R = out_size;             // output is (R,)

    const int NSLICE = (K + SLICE_G - 1) / SLICE_G;   // 8 for K=4096
    const int KPAD   = NSLICE * SLICE_G;

    float* out = (float*)d_out;
    float* gG  = (float*)d_ws;          // (KPAD/4) * 24 floats

    {
        dim3 grid((KPAD + PBLOCK - 1) / PBLOCK);
        precompute_gauss<<<grid, PBLOCK, 0, stream>>>(pos_raw, conc_raw, scale_raw,
                                                      rot_raw, map_size,
                                                      gG, out, K, KPAD, R);
    }
    {
        dim3 grid((R + RPB - 1) / RPB, NSLICE);       // 128 x 8 = 1024 blocks
        splat_main<<<grid, BLOCK, 0, stream>>>(p_rays, u_rays, gG, out, R);
    }
}